// Round 12
// baseline (698.409 us; speedup 1.0000x reference)
//
#include <hip/hip_runtime.h>
#include <stdint.h>

#define TOKENS 8192
#define HIDDEN 4096
constexpr float EPS = 1e-6f;
constexpr float FP8_MAX = 448.0f;

using f32x4  = __attribute__((ext_vector_type(4))) float;
using f32x16 = __attribute__((ext_vector_type(16))) float;
using i32x4  = __attribute__((ext_vector_type(4))) int;
using i32x8  = __attribute__((ext_vector_type(8))) int;

typedef __attribute__((address_space(3))) uint32_t lds_u32_t;
typedef const __attribute__((address_space(1))) uint32_t glb_u32_t;

// ---------------- fp8 pack helper (OCP e4m3fn, RNE + saturate) ----------------
__device__ inline uint32_t pack_fp8x4(float a, float b, float c, float d) {
    int w = 0;
    w = __builtin_amdgcn_cvt_pk_fp8_f32(a, b, w, false); // bytes 0,1
    w = __builtin_amdgcn_cvt_pk_fp8_f32(c, d, w, true);  // bytes 2,3
    return (uint32_t)w;
}

// ---------------- block reductions (4 waves of 64) ----------------
__device__ inline float block_sum(float v, float* sh, int tid) {
#pragma unroll
    for (int o = 32; o > 0; o >>= 1) v += __shfl_xor(v, o, 64);
    if ((tid & 63) == 0) sh[tid >> 6] = v;
    __syncthreads();
    return sh[0] + sh[1] + sh[2] + sh[3];
}
__device__ inline float block_max(float v, float* sh, int tid) {
#pragma unroll
    for (int o = 32; o > 0; o >>= 1) v = fmaxf(v, __shfl_xor(v, o, 64));
    if ((tid & 63) == 0) sh[tid >> 6] = v;
    __syncthreads();
    return fmaxf(fmaxf(sh[0], sh[1]), fmaxf(sh[2], sh[3]));
}

// ---------------- weight quantization: Wq = fp8(W / s), linear layout ----------------
__launch_bounds__(256)
__global__ void quant_weights(const float* __restrict__ Ws,
                              const float* __restrict__ w_scales,
                              uint8_t* __restrict__ Wq) {
    size_t idx = ((size_t)blockIdx.x * 256 + threadIdx.x) * 8;
    int tensor = (int)(idx / ((size_t)HIDDEN * HIDDEN));
    float inv = 1.0f / w_scales[tensor];
    const float4* src = (const float4*)(Ws + idx);
    float4 v0 = src[0], v1 = src[1];
    uint2 out;
    out.x = pack_fp8x4(v0.x * inv, v0.y * inv, v0.z * inv, v0.w * inv);
    out.y = pack_fp8x4(v1.x * inv, v1.y * inv, v1.z * inv, v1.w * inv);
    *(uint2*)(Wq + idx) = out;
}

// ---------------- relu + rmsnorm + dynamic quant (layer 0 input) ----------------
__launch_bounds__(256)
__global__ void relu_rms_quant(const float* __restrict__ x,
                               const float* __restrict__ nw,   // norm_w row 0
                               float* __restrict__ resid,
                               uint8_t* __restrict__ yq,
                               float* __restrict__ ascale) {
    __shared__ float sh1[4], sh2[4];
    const int row = blockIdx.x, tid = threadIdx.x;
    const float* xr = x + (size_t)row * HIDDEN;
    float* rr = resid + (size_t)row * HIDDEN;

    float4 v[4];
    float ss = 0.f;
#pragma unroll
    for (int c = 0; c < 4; ++c) {
        float4 t = *(const float4*)(xr + c * 1024 + tid * 4);
        t.x = fmaxf(t.x, 0.f); t.y = fmaxf(t.y, 0.f);
        t.z = fmaxf(t.z, 0.f); t.w = fmaxf(t.w, 0.f);
        v[c] = t;
        ss += t.x * t.x + t.y * t.y + t.z * t.z + t.w * t.w;
        *(float4*)(rr + c * 1024 + tid * 4) = t;
    }
    ss = block_sum(ss, sh1, tid);
    float rstd = 1.0f / sqrtf(ss * (1.0f / HIDDEN) + EPS);

    float4 y[4];
    float amax = 0.f;
#pragma unroll
    for (int c = 0; c < 4; ++c) {
        float4 w = *(const float4*)(nw + c * 1024 + tid * 4);
        y[c].x = v[c].x * rstd * w.x; amax = fmaxf(amax, fabsf(y[c].x));
        y[c].y = v[c].y * rstd * w.y; amax = fmaxf(amax, fabsf(y[c].y));
        y[c].z = v[c].z * rstd * w.z; amax = fmaxf(amax, fabsf(y[c].z));
        y[c].w = v[c].w * rstd * w.w; amax = fmaxf(amax, fabsf(y[c].w));
    }
    amax = block_max(amax, sh2, tid);
    float s = fmaxf(amax / FP8_MAX, 1e-12f);
    if (tid == 0) ascale[row] = s;
    float inv = 1.0f / s;
#pragma unroll
    for (int c = 0; c < 4; ++c) {
        uint32_t p = pack_fp8x4(y[c].x * inv, y[c].y * inv, y[c].z * inv, y[c].w * inv);
        *(uint32_t*)(yq + (size_t)row * HIDDEN + c * 1024 + tid * 4) = p;
    }
}

// ---------------- rmsnorm + dynamic quant (between layers) ----------------
__launch_bounds__(256)
__global__ void rms_quant(const float* __restrict__ resid,
                          const float* __restrict__ nw,
                          uint8_t* __restrict__ yq,
                          float* __restrict__ ascale) {
    __shared__ float sh1[4], sh2[4];
    const int row = blockIdx.x, tid = threadIdx.x;
    const float* rr = resid + (size_t)row * HIDDEN;

    float4 v[4];
    float ss = 0.f;
#pragma unroll
    for (int c = 0; c < 4; ++c) {
        float4 t = *(const float4*)(rr + c * 1024 + tid * 4);
        v[c] = t;
        ss += t.x * t.x + t.y * t.y + t.z * t.z + t.w * t.w;
    }
    ss = block_sum(ss, sh1, tid);
    float rstd = 1.0f / sqrtf(ss * (1.0f / HIDDEN) + EPS);

    float4 y[4];
    float amax = 0.f;
#pragma unroll
    for (int c = 0; c < 4; ++c) {
        float4 w = *(const float4*)(nw + c * 1024 + tid * 4);
        y[c].x = v[c].x * rstd * w.x; amax = fmaxf(amax, fabsf(y[c].x));
        y[c].y = v[c].y * rstd * w.y; amax = fmaxf(amax, fabsf(y[c].y));
        y[c].z = v[c].z * rstd * w.z; amax = fmaxf(amax, fabsf(y[c].z));
        y[c].w = v[c].w * rstd * w.w; amax = fmaxf(amax, fabsf(y[c].w));
    }
    amax = block_max(amax, sh2, tid);
    float s = fmaxf(amax / FP8_MAX, 1e-12f);
    if (tid == 0) ascale[row] = s;
    float inv = 1.0f / s;
#pragma unroll
    for (int c = 0; c < 4; ++c) {
        uint32_t p = pack_fp8x4(y[c].x * inv, y[c].y * inv, y[c].z * inv, y[c].w * inv);
        *(uint32_t*)(yq + (size_t)row * HIDDEN + c * 1024 + tid * 4) = p;
    }
}

// ---------------- final rmsnorm -> f32 output ----------------
__launch_bounds__(256)
__global__ void rms_final(const float* __restrict__ resid,
                          const float* __restrict__ nw,
                          float* __restrict__ out) {
    __shared__ float sh1[4];
    const int row = blockIdx.x, tid = threadIdx.x;
    const float* rr = resid + (size_t)row * HIDDEN;

    float4 v[4];
    float ss = 0.f;
#pragma unroll
    for (int c = 0; c < 4; ++c) {
        float4 t = *(const float4*)(rr + c * 1024 + tid * 4);
        v[c] = t;
        ss += t.x * t.x + t.y * t.y + t.z * t.z + t.w * t.w;
    }
    ss = block_sum(ss, sh1, tid);
    float rstd = 1.0f / sqrtf(ss * (1.0f / HIDDEN) + EPS);

#pragma unroll
    for (int c = 0; c < 4; ++c) {
        float4 w = *(const float4*)(nw + c * 1024 + tid * 4);
        float4 o;
        o.x = v[c].x * rstd * w.x;
        o.y = v[c].y * rstd * w.y;
        o.z = v[c].z * rstd * w.z;
        o.w = v[c].w * rstd * w.w;
        *(float4*)(out + (size_t)row * HIDDEN + c * 1024 + tid * 4) = o;
    }
}

// ---------------- fp8 GEMM, m201-template port: 256x256, BK=128B, 4-phase ----------------
// resid += a_scale[t]*w_scale * (Aq @ Bq^T).  8 waves (2m x 4n), 128x64/wave,
// 32x32x64 MX-scaled MFMA (unit e8m0 scales), 2 K-instr (j=0,1) per 128B tile.
// dbuf=2 (2 x 64 KB).  Per K-tile, 4 phases, each: {ds_read subtile | stage} ->
// barrier -> lgkmcnt(0) -> setprio(1) 4xMFMA setprio(0) -> barrier.
// Stage: A-halves of t+1 at phi0, B-halves at phi1; vmcnt(0) at phi3 (loads issued
// >=2 phases ago -> lands free).  Race safety (two barriers/phase): reads of slot X
// in phase p are lgkm-drained before p's end-barrier; soonest overwrite of X is
// p+2's pre-barrier region -> no R10-class race with dbuf=2.
// LDS swizzle: [row][g] holds global granule g ^ (row&7); bank = 4*g_stored
// (row*128 = 0 mod 128B) -> 3-bit XOR spreads 8 rows over 8 slots, conflict-free.
#define BM 256
#define BN 256
#define BKB 128

#define MFMA_MX(A, B, C) __builtin_amdgcn_mfma_scale_f32_32x32x64_f8f6f4( \
    (A), (B), (C), 0, 0, 0, 0x7F7F7F7F, 0, 0x7F7F7F7F)

__launch_bounds__(512, 2)
__global__ void gemm_fp8(const uint8_t* __restrict__ Aq,
                         const uint8_t* __restrict__ Bq,
                         const float* __restrict__ ascale,
                         const float* __restrict__ wscale_p,
                         float* __restrict__ resid) {
    __shared__ __align__(16) uint8_t sA[2][BM * BKB];   // 2 x 32 KB
    __shared__ __align__(16) uint8_t sB[2][BN * BKB];   // 2 x 32 KB
    __shared__ float s_as[BM];

    const int tid = threadIdx.x;
    // XCD-chunked bijective swizzle (grid = 512 = 8 * 64)
    int bid = blockIdx.x;
    bid = (bid & 7) * 64 + (bid >> 3);
    const int nbn = HIDDEN / BN;   // 16
    const int bm = bid / nbn, bn = bid % nbn;
    const int brow = bm * BM, bcol = bn * BN;

    const int wave = tid >> 6, lane = tid & 63;
    const int wm = wave >> 2, wn = wave & 3;   // 2 x 4 wave grid
    const int lr = lane & 31;      // row within 32x32 tile
    const int lh = lane >> 5;      // k-half within 64B K-instr

    if (tid < BM) s_as[tid] = ascale[brow + tid];

    f32x16 acc[4][2] = {};

    const uint8_t* aSrc = Aq + (size_t)brow * HIDDEN;
    const uint8_t* bSrc = Bq + (size_t)bcol * HIDDEN;

    // Stager: one issue = 64 rows (512 thr x 16B); thread -> row rowbase+(tid>>3),
    // LDS granule tid&7, global granule (tid&7)^(row&7).
    const int r_th = tid >> 3;                       // 0..63
    const int gsrc = (tid & 7) ^ (r_th & 7);
    const size_t srcOff = (size_t)r_th * HIDDEN + gsrc * 16;
    const int ldsw = wave * 1024;                    // + lane*16 implicit

    // Reader: frag (row, j, h2) at byte row*128 + ((j*4+lh*2+h2) ^ (row&7))*16.
    int offA[4][2][2], offB[2][2][2];
#pragma unroll
    for (int mi = 0; mi < 4; ++mi) {
        const int ra = wm * 128 + mi * 32 + lr, s7 = ra & 7;
#pragma unroll
        for (int j = 0; j < 2; ++j)
#pragma unroll
            for (int h2 = 0; h2 < 2; ++h2)
                offA[mi][j][h2] = ra * BKB + ((j * 4 + lh * 2 + h2) ^ s7) * 16;
    }
#pragma unroll
    for (int ni = 0; ni < 2; ++ni) {
        const int rb = wn * 64 + ni * 32 + lr, s7 = rb & 7;
#pragma unroll
        for (int j = 0; j < 2; ++j)
#pragma unroll
            for (int h2 = 0; h2 < 2; ++h2)
                offB[ni][j][h2] = rb * BKB + ((j * 4 + lh * 2 + h2) ^ s7) * 16;
    }

    auto stageHalves = [&](uint8_t* sdst, const uint8_t* src, int kb) {
        // stage rows 0..255 of one matrix (4 issues of 64 rows)
#pragma unroll
        for (int i = 0; i < 4; ++i) {
            const int rowbase = i * 64;
            __builtin_amdgcn_global_load_lds(
                (glb_u32_t*)(src + (size_t)rowbase * HIDDEN + srcOff + kb),
                (lds_u32_t*)(sdst + rowbase * BKB + ldsw), 16, 0, 0);
        }
    };
    auto rdfrag = [&](const uint8_t* base, const int* off) -> i32x8 {
        i32x4 lo = *(const i32x4*)&base[off[0]];
        i32x4 hi = *(const i32x4*)&base[off[1]];
        return __builtin_shufflevector(lo, hi, 0, 1, 2, 3, 4, 5, 6, 7);
    };

    const int NT = HIDDEN / BKB;   // 32
    // prologue: tile 0 fully staged into buf 0
    stageHalves(sA[0], aSrc, 0);
    stageHalves(sB[0], bSrc, 0);
    asm volatile("s_waitcnt vmcnt(0)" ::: "memory");
    __builtin_amdgcn_s_barrier();

#pragma unroll 1
    for (int t = 0; t < NT; ++t) {
        const int buf = t & 1, nbf = buf ^ 1;
        const int kn = (t + 1) * BKB;
        i32x8 a0, a1, a2, a3, b0, b1;

        // ---- phi0: j=0, mi01 ----
        a0 = rdfrag(sA[buf], offA[0][0]);
        a1 = rdfrag(sA[buf], offA[1][0]);
        b0 = rdfrag(sB[buf], offB[0][0]);
        b1 = rdfrag(sB[buf], offB[1][0]);
        if (t + 1 < NT) stageHalves(sA[nbf], aSrc, kn);
        __builtin_amdgcn_s_barrier();
        asm volatile("s_waitcnt lgkmcnt(0)" ::: "memory");
        __builtin_amdgcn_s_setprio(1);
        acc[0][0] = MFMA_MX(a0, b0, acc[0][0]);
        acc[0][1] = MFMA_MX(a0, b1, acc[0][1]);
        acc[1][0] = MFMA_MX(a1, b0, acc[1][0]);
        acc[1][1] = MFMA_MX(a1, b1, acc[1][1]);
        __builtin_amdgcn_s_setprio(0);
        __builtin_amdgcn_s_barrier();

        // ---- phi1: j=0, mi23 ----
        a2 = rdfrag(sA[buf], offA[2][0]);
        a3 = rdfrag(sA[buf], offA[3][0]);
        if (t + 1 < NT) stageHalves(sB[nbf], bSrc, kn);
        __builtin_amdgcn_s_barrier();
        asm volatile("s_waitcnt lgkmcnt(0)" ::: "memory");
        __builtin_amdgcn_s_setprio(1);
        acc[2][0] = MFMA_MX(a2, b0, acc[2][0]);
        acc[2][1] = MFMA_MX(a2, b1, acc[2][1]);
        acc[3][0] = MFMA_MX(a3, b0, acc[3][0]);
        acc[3][1] = MFMA_MX(a3, b1, acc[3][1]);
        __builtin_amdgcn_s_setprio(0);
        __builtin_amdgcn_s_barrier();

        // ---- phi2: j=1, mi01 ----
        a0 = rdfrag(sA[buf], offA[0][1]);
        a1 = rdfrag(sA[buf], offA[1][1]);
        b0 = rdfrag(sB[buf], offB[0][1]);
        b1 = rdfrag(sB[buf], offB[1][1]);
        __builtin_amdgcn_s_barrier();
        asm volatile("s_waitcnt lgkmcnt(0)" ::: "memory");
        __builtin_amdgcn_s_setprio(1);
        acc[0][0] = MFMA_MX(a0, b0, acc[0][0]);
        acc[0][1] = MFMA_MX(a0, b1, acc[0][1]);
        acc[1][0] = MFMA_MX(a1, b0, acc[1][0]);
        acc[1][1] = MFMA_MX(a1, b1, acc[1][1]);
        __builtin_amdgcn_s_setprio(0);
        __builtin_amdgcn_s_barrier();

        // ---- phi3: j=1, mi23 ----
        a2 = rdfrag(sA[buf], offA[2][1]);
        a3 = rdfrag(sA[buf], offA[3][1]);
        asm volatile("s_waitcnt vmcnt(0)" ::: "memory");  // t+1 loads landed (>=2 phases old)
        __builtin_amdgcn_s_barrier();
        asm volatile("s_waitcnt lgkmcnt(0)" ::: "memory");
        __builtin_amdgcn_s_setprio(1);
        acc[2][0] = MFMA_MX(a2, b0, acc[2][0]);
        acc[2][1] = MFMA_MX(a2, b1, acc[2][1]);
        acc[3][0] = MFMA_MX(a3, b0, acc[3][0]);
        acc[3][1] = MFMA_MX(a3, b1, acc[3][1]);
        __builtin_amdgcn_s_setprio(0);
        __builtin_amdgcn_s_barrier();
    }

    const float wsc = *wscale_p;
#pragma unroll
    for (int mi = 0; mi < 4; ++mi) {
        float alpha[16];
#pragma unroll
        for (int i = 0; i < 16; ++i) {
            const int rl = (i & 3) + 8 * (i >> 2) + 4 * lh;
            alpha[i] = s_as[wm * 128 + mi * 32 + rl] * wsc;
        }
#pragma unroll
        for (int ni = 0; ni < 2; ++ni) {
            const int col = bcol + wn * 64 + ni * 32 + lr;
#pragma unroll
            for (int i = 0; i < 16; ++i) {
                const int rl = (i & 3) + 8 * (i >> 2) + 4 * lh;
                const int row_local = wm * 128 + mi * 32 + rl;
                const size_t o = (size_t)(brow + row_local) * HIDDEN + col;
                resid[o] += acc[mi][ni][i] * alpha[i];
            }
        }
    }
}

// ---------------- launch ----------------
extern "C" void kernel_launch(void* const* d_in, const int* in_sizes, int n_in,
                              void* d_out, int out_size, void* d_ws, size_t ws_size,
                              hipStream_t stream) {
    const float* x   = (const float*)d_in[0];
    const float* nw  = (const float*)d_in[1];
    const float* Ws  = (const float*)d_in[2];
    const float* wsc = (const float*)d_in[3];
    float* out = (float*)d_out;

    uint8_t* ws = (uint8_t*)d_ws;
    float*   resid  = (float*)ws;                                  // 128 MiB
    uint8_t* yq     = ws + (size_t)TOKENS * HIDDEN * 4;            // 32 MiB
    uint8_t* Wq     = yq + (size_t)TOKENS * HIDDEN;                // 48 MiB
    float*   ascale = (float*)(Wq + (size_t)3 * HIDDEN * HIDDEN);  // 32 KiB

    // quantize weights (3 * H * H elements, 8 per thread)
    quant_weights<<<(3 * (size_t)HIDDEN * HIDDEN) / 2048, 256, 0, stream>>>(Ws, wsc, Wq);

    // relu + rmsnorm(norm_w[0]) + quant
    relu_rms_quant<<<TOKENS, 256, 0, stream>>>(x, nw, resid, yq, ascale);

    for (int i = 0; i < 3; ++i) {
        gemm_fp8<<<(TOKENS / BM) * (HIDDEN / BN), 512, 0, stream>>>(
            yq, Wq + (size_t)i * HIDDEN * HIDDEN, ascale, wsc + i, resid);
        if (i < 2)
            rms_quant<<<TOKENS, 256, 0, stream>>>(resid, nw + (size_t)(i + 1) * HIDDEN, yq, ascale);
        else
            rms_final<<<TOKENS, 256, 0, stream>>>(resid, nw + (size_t)3 * HIDDEN, out);
    }
}

// Round 13
// 657.126 us; speedup vs baseline: 1.0628x; 1.0628x over previous
//
#include <hip/hip_runtime.h>
#include <stdint.h>

#define TOKENS 8192
#define HIDDEN 4096
constexpr float EPS = 1e-6f;
constexpr float FP8_MAX = 448.0f;

using f32x4  = __attribute__((ext_vector_type(4))) float;
using f32x16 = __attribute__((ext_vector_type(16))) float;
using i32x4  = __attribute__((ext_vector_type(4))) int;
using i32x8  = __attribute__((ext_vector_type(8))) int;

typedef __attribute__((address_space(3))) uint32_t lds_u32_t;
typedef const __attribute__((address_space(1))) uint32_t glb_u32_t;

// ---------------- fp8 pack helper (OCP e4m3fn, RNE + saturate) ----------------
__device__ inline uint32_t pack_fp8x4(float a, float b, float c, float d) {
    int w = 0;
    w = __builtin_amdgcn_cvt_pk_fp8_f32(a, b, w, false); // bytes 0,1
    w = __builtin_amdgcn_cvt_pk_fp8_f32(c, d, w, true);  // bytes 2,3
    return (uint32_t)w;
}

// ---------------- block reductions (4 waves of 64) ----------------
__device__ inline float block_sum(float v, float* sh, int tid) {
#pragma unroll
    for (int o = 32; o > 0; o >>= 1) v += __shfl_xor(v, o, 64);
    if ((tid & 63) == 0) sh[tid >> 6] = v;
    __syncthreads();
    return sh[0] + sh[1] + sh[2] + sh[3];
}
__device__ inline float block_max(float v, float* sh, int tid) {
#pragma unroll
    for (int o = 32; o > 0; o >>= 1) v = fmaxf(v, __shfl_xor(v, o, 64));
    if ((tid & 63) == 0) sh[tid >> 6] = v;
    __syncthreads();
    return fmaxf(fmaxf(sh[0], sh[1]), fmaxf(sh[2], sh[3]));
}

// ---------------- weight quantization: Wq = fp8(W / s), linear layout ----------------
__launch_bounds__(256)
__global__ void quant_weights(const float* __restrict__ Ws,
                              const float* __restrict__ w_scales,
                              uint8_t* __restrict__ Wq) {
    size_t idx = ((size_t)blockIdx.x * 256 + threadIdx.x) * 8;
    int tensor = (int)(idx / ((size_t)HIDDEN * HIDDEN));
    float inv = 1.0f / w_scales[tensor];
    const float4* src = (const float4*)(Ws + idx);
    float4 v0 = src[0], v1 = src[1];
    uint2 out;
    out.x = pack_fp8x4(v0.x * inv, v0.y * inv, v0.z * inv, v0.w * inv);
    out.y = pack_fp8x4(v1.x * inv, v1.y * inv, v1.z * inv, v1.w * inv);
    *(uint2*)(Wq + idx) = out;
}

// ---------------- relu + rmsnorm + dynamic quant (layer 0 input) ----------------
__launch_bounds__(256)
__global__ void relu_rms_quant(const float* __restrict__ x,
                               const float* __restrict__ nw,   // norm_w row 0
                               float* __restrict__ resid,
                               uint8_t* __restrict__ yq,
                               float* __restrict__ ascale) {
    __shared__ float sh1[4], sh2[4];
    const int row = blockIdx.x, tid = threadIdx.x;
    const float* xr = x + (size_t)row * HIDDEN;
    float* rr = resid + (size_t)row * HIDDEN;

    float4 v[4];
    float ss = 0.f;
#pragma unroll
    for (int c = 0; c < 4; ++c) {
        float4 t = *(const float4*)(xr + c * 1024 + tid * 4);
        t.x = fmaxf(t.x, 0.f); t.y = fmaxf(t.y, 0.f);
        t.z = fmaxf(t.z, 0.f); t.w = fmaxf(t.w, 0.f);
        v[c] = t;
        ss += t.x * t.x + t.y * t.y + t.z * t.z + t.w * t.w;
        *(float4*)(rr + c * 1024 + tid * 4) = t;
    }
    ss = block_sum(ss, sh1, tid);
    float rstd = 1.0f / sqrtf(ss * (1.0f / HIDDEN) + EPS);

    float4 y[4];
    float amax = 0.f;
#pragma unroll
    for (int c = 0; c < 4; ++c) {
        float4 w = *(const float4*)(nw + c * 1024 + tid * 4);
        y[c].x = v[c].x * rstd * w.x; amax = fmaxf(amax, fabsf(y[c].x));
        y[c].y = v[c].y * rstd * w.y; amax = fmaxf(amax, fabsf(y[c].y));
        y[c].z = v[c].z * rstd * w.z; amax = fmaxf(amax, fabsf(y[c].z));
        y[c].w = v[c].w * rstd * w.w; amax = fmaxf(amax, fabsf(y[c].w));
    }
    amax = block_max(amax, sh2, tid);
    float s = fmaxf(amax / FP8_MAX, 1e-12f);
    if (tid == 0) ascale[row] = s;
    float inv = 1.0f / s;
#pragma unroll
    for (int c = 0; c < 4; ++c) {
        uint32_t p = pack_fp8x4(y[c].x * inv, y[c].y * inv, y[c].z * inv, y[c].w * inv);
        *(uint32_t*)(yq + (size_t)row * HIDDEN + c * 1024 + tid * 4) = p;
    }
}

// ---------------- rmsnorm + dynamic quant (between layers) ----------------
__launch_bounds__(256)
__global__ void rms_quant(const float* __restrict__ resid,
                          const float* __restrict__ nw,
                          uint8_t* __restrict__ yq,
                          float* __restrict__ ascale) {
    __shared__ float sh1[4], sh2[4];
    const int row = blockIdx.x, tid = threadIdx.x;
    const float* rr = resid + (size_t)row * HIDDEN;

    float4 v[4];
    float ss = 0.f;
#pragma unroll
    for (int c = 0; c < 4; ++c) {
        float4 t = *(const float4*)(rr + c * 1024 + tid * 4);
        v[c] = t;
        ss += t.x * t.x + t.y * t.y + t.z * t.z + t.w * t.w;
    }
    ss = block_sum(ss, sh1, tid);
    float rstd = 1.0f / sqrtf(ss * (1.0f / HIDDEN) + EPS);

    float4 y[4];
    float amax = 0.f;
#pragma unroll
    for (int c = 0; c < 4; ++c) {
        float4 w = *(const float4*)(nw + c * 1024 + tid * 4);
        y[c].x = v[c].x * rstd * w.x; amax = fmaxf(amax, fabsf(y[c].x));
        y[c].y = v[c].y * rstd * w.y; amax = fmaxf(amax, fabsf(y[c].y));
        y[c].z = v[c].z * rstd * w.z; amax = fmaxf(amax, fabsf(y[c].z));
        y[c].w = v[c].w * rstd * w.w; amax = fmaxf(amax, fabsf(y[c].w));
    }
    amax = block_max(amax, sh2, tid);
    float s = fmaxf(amax / FP8_MAX, 1e-12f);
    if (tid == 0) ascale[row] = s;
    float inv = 1.0f / s;
#pragma unroll
    for (int c = 0; c < 4; ++c) {
        uint32_t p = pack_fp8x4(y[c].x * inv, y[c].y * inv, y[c].z * inv, y[c].w * inv);
        *(uint32_t*)(yq + (size_t)row * HIDDEN + c * 1024 + tid * 4) = p;
    }
}

// ---------------- final rmsnorm -> f32 output ----------------
__launch_bounds__(256)
__global__ void rms_final(const float* __restrict__ resid,
                          const float* __restrict__ nw,
                          float* __restrict__ out) {
    __shared__ float sh1[4];
    const int row = blockIdx.x, tid = threadIdx.x;
    const float* rr = resid + (size_t)row * HIDDEN;

    float4 v[4];
    float ss = 0.f;
#pragma unroll
    for (int c = 0; c < 4; ++c) {
        float4 t = *(const float4*)(rr + c * 1024 + tid * 4);
        v[c] = t;
        ss += t.x * t.x + t.y * t.y + t.z * t.z + t.w * t.w;
    }
    ss = block_sum(ss, sh1, tid);
    float rstd = 1.0f / sqrtf(ss * (1.0f / HIDDEN) + EPS);

#pragma unroll
    for (int c = 0; c < 4; ++c) {
        float4 w = *(const float4*)(nw + c * 1024 + tid * 4);
        float4 o;
        o.x = v[c].x * rstd * w.x;
        o.y = v[c].y * rstd * w.y;
        o.z = v[c].z * rstd * w.z;
        o.w = v[c].w * rstd * w.w;
        *(float4*)(out + (size_t)row * HIDDEN + c * 1024 + tid * 4) = o;
    }
}

// ---------------- fp8 GEMM, 256x256, R8 structure + fully-static 4x unroll ----------------
// resid += a_scale[t]*w_scale * (Aq @ Bq^T).  8 waves (2m x 4n), 128x64/wave,
// 32x32x64 MX-scaled MFMA, unit e8m0 scales.  NBUF=4, stage 2 tiles ahead,
// counted vmcnt(8) (never 0 in main loop), 1 barrier/tile — exactly R8's proven
// schedule.  Change: K-loop unrolled 4x so every buffer index is a compile-time
// constant -> LDS bases fold into ds_read immediates, the 12 swizzled offsets and
// buffer pointers stop being rematerialized every tile (R8: VALUBusy 10.4% ~= 364
// VALU-cyc/tile of pure addressing).
#define BM 256
#define BN 256
#define BK 64
#define NBUF 4

__launch_bounds__(512, 2)
__global__ void gemm_fp8(const uint8_t* __restrict__ Aq,
                         const uint8_t* __restrict__ Bq,
                         const float* __restrict__ ascale,
                         const float* __restrict__ wscale_p,
                         float* __restrict__ resid) {
    __shared__ __align__(16) uint8_t sA[NBUF][BM * BK];   // 4 x 16 KB
    __shared__ __align__(16) uint8_t sB[NBUF][BN * BK];   // 4 x 16 KB
    __shared__ float s_as[BM];

    const int tid = threadIdx.x;
    // XCD-chunked bijective swizzle (grid = 512 = 8 * 64)
    int bid = blockIdx.x;
    bid = (bid & 7) * 64 + (bid >> 3);
    const int nbn = HIDDEN / BN;   // 16
    const int bm = bid / nbn, bn = bid % nbn;
    const int brow = bm * BM, bcol = bn * BN;

    const int wave = tid >> 6, lane = tid & 63;
    const int wm = wave >> 2, wn = wave & 3;   // 2 x 4 wave grid
    const int lr = lane & 31;      // row within 32x32 tile
    const int lh = lane >> 5;      // k-half (which 32B k-block)

    if (tid < BM) s_as[tid] = ascale[brow + tid];

    f32x16 acc[4][2] = {};

    const uint8_t* aSrc = Aq + (size_t)brow * HIDDEN;
    const uint8_t* bSrc = Bq + (size_t)bcol * HIDDEN;

    // Stager: issue c covers LDS bytes c*8192 + tid*16 -> row = c*128 + (tid>>2),
    // granule = tid&3.  LDS[r][g] holds global granule g ^ ((r>>1)&3).
    const int r_st = tid >> 2;            // 0..127
    const int g_st = tid & 3;
    const int gsrc = g_st ^ ((r_st >> 1) & 3);
    const size_t off0 = (size_t)r_st * HIDDEN + gsrc * 16;
    const size_t off1 = (size_t)(r_st + 128) * HIDDEN + gsrc * 16;
    const int ldsw = wave * 1024;         // + lane*16 implicit (uniform base per wave)

    // Reader: lane fragment = 32 contiguous k-bytes of one row, two b128s at
    // swizzled granules (2*lh+h) ^ ((row>>1)&3).
    int offA[4][2], offB[2][2];
#pragma unroll
    for (int mi = 0; mi < 4; ++mi) {
        int ra = wm * 128 + mi * 32 + lr;
        int sw = (ra >> 1) & 3;
        offA[mi][0] = ra * 64 + ((2 * lh + 0) ^ sw) * 16;
        offA[mi][1] = ra * 64 + ((2 * lh + 1) ^ sw) * 16;
    }
#pragma unroll
    for (int ni = 0; ni < 2; ++ni) {
        int rb = wn * 64 + ni * 32 + lr;
        int sw = (rb >> 1) & 3;
        offB[ni][0] = rb * 64 + ((2 * lh + 0) ^ sw) * 16;
        offB[ni][1] = rb * 64 + ((2 * lh + 1) ^ sw) * 16;
    }

    const int UNIT = 0x7F7F7F7F;  // e8m0 scale = 2^0 in all bytes

    auto stage = [&](int buf, int kt) {
        const int k0 = kt * BK;
        __builtin_amdgcn_global_load_lds((glb_u32_t*)(aSrc + off0 + k0),
                                         (lds_u32_t*)&sA[buf][ldsw], 16, 0, 0);
        __builtin_amdgcn_global_load_lds((glb_u32_t*)(aSrc + off1 + k0),
                                         (lds_u32_t*)&sA[buf][8192 + ldsw], 16, 0, 0);
        __builtin_amdgcn_global_load_lds((glb_u32_t*)(bSrc + off0 + k0),
                                         (lds_u32_t*)&sB[buf][ldsw], 16, 0, 0);
        __builtin_amdgcn_global_load_lds((glb_u32_t*)(bSrc + off1 + k0),
                                         (lds_u32_t*)&sB[buf][8192 + ldsw], 16, 0, 0);
    };
    auto rdfrag = [&](const uint8_t* base, const int* off) -> i32x8 {
        i32x4 lo = *(const i32x4*)&base[off[0]];
        i32x4 hi = *(const i32x4*)&base[off[1]];
        return __builtin_shufflevector(lo, hi, 0, 1, 2, 3, 4, 5, 6, 7);
    };
    // Interleaved compute: B frags first, then per-mi {read A, 2 MFMA}.
    auto compute = [&](int buf) {
        i32x8 b0 = rdfrag(sB[buf], offB[0]);
        i32x8 b1 = rdfrag(sB[buf], offB[1]);
        i32x8 a0 = rdfrag(sA[buf], offA[0]);
        __builtin_amdgcn_s_setprio(1);
        acc[0][0] = __builtin_amdgcn_mfma_scale_f32_32x32x64_f8f6f4(
            a0, b0, acc[0][0], 0, 0, 0, UNIT, 0, UNIT);
        i32x8 a1 = rdfrag(sA[buf], offA[1]);
        acc[0][1] = __builtin_amdgcn_mfma_scale_f32_32x32x64_f8f6f4(
            a0, b1, acc[0][1], 0, 0, 0, UNIT, 0, UNIT);
        i32x8 a2 = rdfrag(sA[buf], offA[2]);
        acc[1][0] = __builtin_amdgcn_mfma_scale_f32_32x32x64_f8f6f4(
            a1, b0, acc[1][0], 0, 0, 0, UNIT, 0, UNIT);
        i32x8 a3 = rdfrag(sA[buf], offA[3]);
        acc[1][1] = __builtin_amdgcn_mfma_scale_f32_32x32x64_f8f6f4(
            a1, b1, acc[1][1], 0, 0, 0, UNIT, 0, UNIT);
        acc[2][0] = __builtin_amdgcn_mfma_scale_f32_32x32x64_f8f6f4(
            a2, b0, acc[2][0], 0, 0, 0, UNIT, 0, UNIT);
        acc[2][1] = __builtin_amdgcn_mfma_scale_f32_32x32x64_f8f6f4(
            a2, b1, acc[2][1], 0, 0, 0, UNIT, 0, UNIT);
        acc[3][0] = __builtin_amdgcn_mfma_scale_f32_32x32x64_f8f6f4(
            a3, b0, acc[3][0], 0, 0, 0, UNIT, 0, UNIT);
        acc[3][1] = __builtin_amdgcn_mfma_scale_f32_32x32x64_f8f6f4(
            a3, b1, acc[3][1], 0, 0, 0, UNIT, 0, UNIT);
        __builtin_amdgcn_s_setprio(0);
    };

    const int NT = HIDDEN / BK;   // 64
    // prologue: tiles 0,1 in flight (8 loads)
    stage(0, 0);
    stage(1, 1);

    // main loop: t = 0..59, fully unrolled x4 -> all buffer indices static.
#pragma unroll 1
    for (int t = 0; t < NT - 4; t += 4) {
#pragma unroll
        for (int k = 0; k < 4; ++k) {
            stage((k + 2) & 3, t + k + 2);                   // always valid: t+k+2 <= 61
            asm volatile("s_waitcnt vmcnt(8)" ::: "memory"); // tile t+k landed
            __builtin_amdgcn_s_barrier();
            compute(k);
        }
    }
    // tail: tiles 60..63 (static bufs 0..3)
    stage(2, 62);
    asm volatile("s_waitcnt vmcnt(8)" ::: "memory");
    __builtin_amdgcn_s_barrier();
    compute(0);
    stage(3, 63);
    asm volatile("s_waitcnt vmcnt(8)" ::: "memory");
    __builtin_amdgcn_s_barrier();
    compute(1);
    asm volatile("s_waitcnt vmcnt(4)" ::: "memory");
    __builtin_amdgcn_s_barrier();
    compute(2);
    asm volatile("s_waitcnt vmcnt(0)" ::: "memory");
    __builtin_amdgcn_s_barrier();
    compute(3);

    const float wsc = *wscale_p;
#pragma unroll
    for (int mi = 0; mi < 4; ++mi) {
        float alpha[16];
#pragma unroll
        for (int i = 0; i < 16; ++i) {
            const int rl = (i & 3) + 8 * (i >> 2) + 4 * lh;
            alpha[i] = s_as[wm * 128 + mi * 32 + rl] * wsc;
        }
#pragma unroll
        for (int ni = 0; ni < 2; ++ni) {
            const int col = bcol + wn * 64 + ni * 32 + lr;
#pragma unroll
            for (int i = 0; i < 16; ++i) {
                const int rl = (i & 3) + 8 * (i >> 2) + 4 * lh;
                const int row_local = wm * 128 + mi * 32 + rl;
                const size_t o = (size_t)(brow + row_local) * HIDDEN + col;
                resid[o] += acc[mi][ni][i] * alpha[i];
            }
        }
    }
}

// ---------------- launch ----------------
extern "C" void kernel_launch(void* const* d_in, const int* in_sizes, int n_in,
                              void* d_out, int out_size, void* d_ws, size_t ws_size,
                              hipStream_t stream) {
    const float* x   = (const float*)d_in[0];
    const float* nw  = (const float*)d_in[1];
    const float* Ws  = (const float*)d_in[2];
    const float* wsc = (const float*)d_in[3];
    float* out = (float*)d_out;

    uint8_t* ws = (uint8_t*)d_ws;
    float*   resid  = (float*)ws;                                  // 128 MiB
    uint8_t* yq     = ws + (size_t)TOKENS * HIDDEN * 4;            // 32 MiB
    uint8_t* Wq     = yq + (size_t)TOKENS * HIDDEN;                // 48 MiB
    float*   ascale = (float*)(Wq + (size_t)3 * HIDDEN * HIDDEN);  // 32 KiB

    // quantize weights (3 * H * H elements, 8 per thread)
    quant_weights<<<(3 * (size_t)HIDDEN * HIDDEN) / 2048, 256, 0, stream>>>(Ws, wsc, Wq);

    // relu + rmsnorm(norm_w[0]) + quant
    relu_rms_quant<<<TOKENS, 256, 0, stream>>>(x, nw, resid, yq, ascale);

    for (int i = 0; i < 3; ++i) {
        gemm_fp8<<<(TOKENS / BM) * (HIDDEN / BN), 512, 0, stream>>>(
            yq, Wq + (size_t)i * HIDDEN * HIDDEN, ascale, wsc + i, resid);
        if (i < 2)
            rms_quant<<<TOKENS, 256, 0, stream>>>(resid, nw + (size_t)(i + 1) * HIDDEN, yq, ascale);
        else
            rms_final<<<TOKENS, 256, 0, stream>>>(resid, nw + (size_t)3 * HIDDEN, out);
    }
}